// Round 4
// baseline (261.835 us; speedup 1.0000x reference)
//
#include <hip/hip_runtime.h>
#include <math.h>

#define HH 4      // heads
#define DD 32     // out dim per head
#define HD 128    // H*D
#define INF 128   // node in_dim
#define EDF 64    // edge feat dim
#define NEG 0.01f
#define NB 256    // scan blocks
#define ONODES 64 // nodes per k_out block
#define CHUNK 64  // edges per k_agg chunk

// ---- DPP butterfly add within rows of 16 lanes (VALU, no LDS) -----------
template <int CTRL>
__device__ __forceinline__ float dpp_add(float v) {
    int t = __builtin_amdgcn_update_dpp(0, __float_as_int(v), CTRL, 0xF, 0xF, true);
    return v + __int_as_float(t);
}
__device__ __forceinline__ float red16(float v) {
    v = dpp_add<0xB1>(v);    // quad_perm(1,0,3,2)
    v = dpp_add<0x4E>(v);    // quad_perm(2,3,0,1)
    v = dpp_add<0x141>(v);   // row_half_mirror
    v = dpp_add<0x140>(v);   // row_mirror
    return v;
}

// ---- precompute collapsed weight matrices -------------------------------
__global__ void k_pre(const float* __restrict__ Wn, const float* __restrict__ We,
                      const float* __restrict__ Wa, const float* __restrict__ Wo,
                      float* __restrict__ WnA, float* __restrict__ WnB,
                      float* __restrict__ WeC, float* __restrict__ WeWo,
                      float* __restrict__ WnWo) {
    int b = blockIdx.x, tid = threadIdx.x;   // 25 blocks x 512
    if (b < 16) {
        int t = b * 512 + tid;               // t = (h*64+k)*32 + o
        int j = t >> 5, o = t & 31;
        int h = j >> 6, k = j & 63;
        float a = 0.f;
        for (int d = 0; d < DD; ++d)
            a += We[k * HD + h * DD + d] * Wo[(h * DD + d) * DD + o];
        WeWo[t] = a;
    } else if (b < 24) {
        int u = (b - 16) * 512 + tid;        // u = k*32 + o
        int k = u >> 5, o = u & 31;
        float a = 0.f;
        for (int d = 0; d < HD; ++d)
            a += Wn[k * HD + d] * Wo[d * DD + o];
        WnWo[u] = a;
    } else {
        int k = tid >> 2, h = tid & 3;
        float a = 0.f, bb = 0.f;
        for (int d = 0; d < DD; ++d) {
            float w = Wn[k * HD + h * DD + d];
            a += w * Wa[d];
            bb += w * Wa[DD + d];
        }
        WnA[k * HH + h] = a;
        WnB[k * HH + h] = bb;
        if (k < EDF) {
            float c = 0.f;
            for (int d = 0; d < DD; ++d)
                c += We[k * HD + h * DD + d] * (Wa[d] + Wa[DD + d]);
            WeC[k * HH + h] = c;
        }
    }
}

// ---- per-node attention scalars an,bn (wave per node) -------------------
__global__ void k_nodes(const float* __restrict__ X, const float* __restrict__ WnA,
                        const float* __restrict__ WnB, float* __restrict__ an,
                        float* __restrict__ bn, int N) {
    int wave = threadIdx.x >> 6, lane = threadIdx.x & 63;
    int n = blockIdx.x * 4 + wave;
    if (n >= N) return;
    float x0 = X[(size_t)n * INF + lane];
    float x1 = X[(size_t)n * INF + 64 + lane];
    float pa[HH], pb[HH];
#pragma unroll
    for (int h = 0; h < HH; ++h) {
        pa[h] = x0 * WnA[lane * HH + h] + x1 * WnA[(lane + 64) * HH + h];
        pb[h] = x0 * WnB[lane * HH + h] + x1 * WnB[(lane + 64) * HH + h];
    }
#pragma unroll
    for (int off = 32; off; off >>= 1)
#pragma unroll
        for (int h = 0; h < HH; ++h) {
            pa[h] += __shfl_xor(pa[h], off);
            pb[h] += __shfl_xor(pb[h], off);
        }
    if (lane == 0)
#pragma unroll
        for (int h = 0; h < HH; ++h) {
            an[(size_t)n * HH + h] = pa[h];
            bn[(size_t)n * HH + h] = pb[h];
        }
}

// ---- CSR build ----------------------------------------------------------
__global__ void k_init(int* __restrict__ deg, int N) {
    int i = blockIdx.x * blockDim.x + threadIdx.x;
    if (i < N) deg[i] = 0;
}
__global__ void k_hist(const int* __restrict__ dst, int* __restrict__ deg,
                       int* __restrict__ rank, int E) {
    int e = blockIdx.x * blockDim.x + threadIdx.x;
    if (e < E) rank[e] = atomicAdd(&deg[dst[e]], 1);
}
__global__ void k_scan1(const int* __restrict__ deg, int* __restrict__ partial,
                        int N, int chunk) {
    __shared__ int s[256];
    int tid = threadIdx.x;
    int i = blockIdx.x * chunk + tid;
    int v = (tid < chunk && i < N) ? deg[i] : 0;
    s[tid] = v; __syncthreads();
    for (int off = 128; off; off >>= 1) {
        if (tid < off) s[tid] += s[tid + off];
        __syncthreads();
    }
    if (tid == 0) partial[blockIdx.x] = s[0];
}
__global__ void k_scan2(const int* __restrict__ partial, int* __restrict__ pscan) {
    __shared__ int s[NB];
    int tid = threadIdx.x;
    int v = partial[tid];
    s[tid] = v; __syncthreads();
    for (int off = 1; off < NB; off <<= 1) {
        int t = (tid >= off) ? s[tid - off] : 0;
        __syncthreads();
        s[tid] += t;
        __syncthreads();
    }
    pscan[tid] = s[tid] - v;   // exclusive
}
// also packs nd[i] = {offs, deg} so k_agg loads node meta in ONE int2
__global__ void k_scan3(const int* __restrict__ deg, const int* __restrict__ pscan,
                        int* __restrict__ offs, int2* __restrict__ nd,
                        int N, int chunk) {
    __shared__ int s[256];
    int tid = threadIdx.x;
    int i = blockIdx.x * chunk + tid;
    int v = (tid < chunk && i < N) ? deg[i] : 0;
    s[tid] = v; __syncthreads();
    for (int off = 1; off < 256; off <<= 1) {
        int t = (tid >= off) ? s[tid - off] : 0;
        __syncthreads();
        s[tid] += t;
        __syncthreads();
    }
    if (tid < chunk && i < N) {
        int o = pscan[blockIdx.x] + s[tid] - v;   // exclusive
        offs[i] = o;
        nd[i] = make_int2(o, v);
    }
}
// inverse permutation: CSR slot for each edge (coalesced read+write)
__global__ void k_pos(const int* __restrict__ dst, const int* __restrict__ offs,
                      const int* __restrict__ rank, int* __restrict__ pos_of, int E) {
    int e = blockIdx.x * blockDim.x + threadIdx.x;
    if (e < E) pos_of[e] = offs[dst[e]] + rank[e];
}

// ---- edge-parallel logits + CSR scatter ---------------------------------
// wave handles 4 consecutive edges; 16 lanes per edge. Computes
// w4 = exp(leaky(an[src]+bn[dst]+EF.WeC)) and scatter-writes BOTH the
// weight (wep[pos]) and the full EF row (EFp[pos], 256B full-line store)
// into CSR order. Stores are fire-and-forget: no latency exposure here,
// and k_agg becomes fully coalesced.
__global__ void k_logit(const float* __restrict__ EF, const float* __restrict__ an,
                        const float* __restrict__ bn, const float* __restrict__ WeC,
                        const int* __restrict__ src, const int* __restrict__ dst,
                        const int* __restrict__ pos_of,
                        float* __restrict__ wep, float* __restrict__ EFp, int E) {
    __shared__ float wec_s[EDF * HH];
    if (threadIdx.x < EDF * HH) wec_s[threadIdx.x] = WeC[threadIdx.x];
    __syncthreads();
    int wave = threadIdx.x >> 6, lane = threadIdx.x & 63;
    int g = lane >> 4, q = lane & 15;
    int e = (blockIdx.x * 4 + wave) * 4 + g;
    if (e >= E) return;
    float wc[4][4];
#pragma unroll
    for (int c = 0; c < 4; ++c)
#pragma unroll
        for (int h = 0; h < 4; ++h)
            wc[c][h] = wec_s[(q * 4 + c) * 4 + h];
    float4 x4 = *(const float4*)(EF + (size_t)e * EDF + q * 4);
    int s = src[e], d = dst[e], p = pos_of[e];
    float4 an4 = *(const float4*)(an + (size_t)s * HH);
    float4 bn4 = *(const float4*)(bn + (size_t)d * HH);
    float ae[4];
#pragma unroll
    for (int h = 0; h < 4; ++h) {
        float p0 = x4.x * wc[0][h] + x4.y * wc[1][h]
                 + x4.z * wc[2][h] + x4.w * wc[3][h];
        ae[h] = red16(p0);
    }
    // scatter EF row into CSR order (16 lanes = 256B, 4 full lines)
    *(float4*)(EFp + (size_t)p * EDF + q * 4) = x4;
    if (q == 0) {
        float l0 = an4.x + bn4.x + ae[0];
        float l1 = an4.y + bn4.y + ae[1];
        float l2 = an4.z + bn4.z + ae[2];
        float l3 = an4.w + bn4.w + ae[3];
        float4 w4;
        w4.x = __expf(l0 > 0.f ? l0 : NEG * l0);
        w4.y = __expf(l1 > 0.f ? l1 : NEG * l1);
        w4.z = __expf(l2 > 0.f ? l2 : NEG * l2);
        w4.w = __expf(l3 > 0.f ? l3 : NEG * l3);
        *(float4*)(wep + (size_t)p * 4) = w4;
    }
}

// ---- aggregation, v5: fully coalesced streaming -------------------------
// wave per node. wep[st..] contiguous; EFp rows contiguous per node.
// lane = feature; zero gathers, zero cross-lane ops.
__global__ void k_agg(const float* __restrict__ EFp, const float* __restrict__ wep,
                      const int2* __restrict__ nd, float* __restrict__ Ghat, int N) {
    __shared__ float4 wbuf[4][CHUNK];
    int wave = threadIdx.x >> 6, lane = threadIdx.x & 63;
    int n = blockIdx.x * 4 + wave;
    if (n >= N) return;
    int2 sd = nd[n];
    int st = sd.x, dn = sd.y;
    if (dn == 0) return;                     // k_out falls back to Wn path

    const float* base = EFp + lane;
    float gacc[4] = {0.f, 0.f, 0.f, 0.f};
    float den[4]  = {0.f, 0.f, 0.f, 0.f};

    for (int r0 = 0; r0 < dn; r0 += CHUNK) {
        int cnt = dn - r0; if (cnt > CHUNK) cnt = CHUNK;
        // stage weights: contiguous 1KB read, zero pads
        {
            int l2 = lane < cnt ? lane : cnt - 1;
            float4 w4 = *(const float4*)(wep + (size_t)(st + r0 + l2) * 4);
            if (lane >= cnt) w4 = make_float4(0.f, 0.f, 0.f, 0.f);
            wbuf[wave][lane] = w4;
        }
        int nb4 = (cnt + 3) >> 2;
        // 2-deep prefetch over contiguous 256B rows
        float x0[4], x1[4], x2[4];
#pragma unroll
        for (int j = 0; j < 4; ++j) {
            int r = r0 + j; r = r < dn ? r : dn - 1;
            x0[j] = base[(size_t)(st + r) * EDF];
        }
#pragma unroll
        for (int j = 0; j < 4; ++j) {
            int r = r0 + 4 + j; r = r < dn ? r : dn - 1;
            x1[j] = base[(size_t)(st + r) * EDF];
        }
        for (int i = 0; i < nb4; ++i) {
#pragma unroll
            for (int j = 0; j < 4; ++j) {
                int r = r0 + (i + 2) * 4 + j; r = r < dn ? r : dn - 1;
                x2[j] = base[(size_t)(st + r) * EDF];
            }
            float4 wA = wbuf[wave][i * 4 + 0];
            float4 wB = wbuf[wave][i * 4 + 1];
            float4 wC = wbuf[wave][i * 4 + 2];
            float4 wD = wbuf[wave][i * 4 + 3];
            gacc[0] += wA.x * x0[0] + wB.x * x0[1] + wC.x * x0[2] + wD.x * x0[3];
            gacc[1] += wA.y * x0[0] + wB.y * x0[1] + wC.y * x0[2] + wD.y * x0[3];
            gacc[2] += wA.z * x0[0] + wB.z * x0[1] + wC.z * x0[2] + wD.z * x0[3];
            gacc[3] += wA.w * x0[0] + wB.w * x0[1] + wC.w * x0[2] + wD.w * x0[3];
            den[0] += wA.x + wB.x + wC.x + wD.x;
            den[1] += wA.y + wB.y + wC.y + wD.y;
            den[2] += wA.z + wB.z + wC.z + wD.z;
            den[3] += wA.w + wB.w + wC.w + wD.w;
#pragma unroll
            for (int j = 0; j < 4; ++j) { x0[j] = x1[j]; x1[j] = x2[j]; }
        }
    }
#pragma unroll
    for (int h = 0; h < 4; ++h)
        Ghat[(size_t)n * 256 + h * 64 + lane] = gacc[h] / den[h];
}

// ---- epilogue GEMM: out[n][o] = relu( sum_j Ghat[n][j] * WeWo[j][o] ) ---
__global__ void k_out(const float* __restrict__ G, const float* __restrict__ WW,
                      const float* __restrict__ X, const float* __restrict__ WnWo,
                      const int* __restrict__ deg, float* __restrict__ out, int N) {
    __shared__ float4 gs[ONODES * 64];       // 64 rows x 256 floats = 64KB
    int tid = threadIdx.x;
    int nb0 = blockIdx.x * ONODES;
    int nrem = N - nb0;
    int nloc = nrem < ONODES ? nrem : ONODES;
    const float4* Gbase = (const float4*)G + (size_t)nb0 * 64;
    for (int i = tid; i < nloc * 64; i += 256)
        gs[i] = Gbase[i];
    __syncthreads();
    int o = tid & 31, grp = tid >> 5;        // 8 groups x 8 nodes
    int t0 = grp * 8;
    float acc[8] = {0.f, 0.f, 0.f, 0.f, 0.f, 0.f, 0.f, 0.f};
    for (int j4 = 0; j4 < 64; ++j4) {
        float w0 = WW[(j4 * 4 + 0) * 32 + o];
        float w1 = WW[(j4 * 4 + 1) * 32 + o];
        float w2 = WW[(j4 * 4 + 2) * 32 + o];
        float w3 = WW[(j4 * 4 + 3) * 32 + o];
#pragma unroll
        for (int t = 0; t < 8; ++t) {
            float4 gv = gs[(t0 + t) * 64 + j4];
            acc[t] += gv.x * w0 + gv.y * w1 + gv.z * w2 + gv.w * w3;
        }
    }
#pragma unroll
    for (int t = 0; t < 8; ++t) {
        int n = nb0 + t0 + t;
        if (n >= N) break;
        float a = acc[t];
        if (deg[n] == 0) {                   // rare: z = X @ (Wn*Wo)
            a = 0.f;
            for (int k = 0; k < INF; ++k)
                a += X[(size_t)n * INF + k] * WnWo[k * DD + o];
        }
        out[(size_t)n * DD + o] = fmaxf(a, 0.f);
    }
}

extern "C" void kernel_launch(void* const* d_in, const int* in_sizes, int n_in,
                              void* d_out, int out_size, void* d_ws, size_t ws_size,
                              hipStream_t stream) {
    const float* node_feats = (const float*)d_in[0];
    const float* edge_feats = (const float*)d_in[1];
    const int*   src        = (const int*)d_in[2];
    const int*   dst        = (const int*)d_in[3];
    const float* Wn         = (const float*)d_in[4];
    const float* We         = (const float*)d_in[5];
    const float* Wa         = (const float*)d_in[6];
    const float* Wo         = (const float*)d_in[7];
    float* out = (float*)d_out;
    int N = in_sizes[0] / INF;
    int E = in_sizes[2];

    char* p = (char*)d_ws;
    auto alloc = [&](size_t bytes) {
        char* r = p;
        p += (bytes + 255) & ~(size_t)255;
        return r;
    };
    float* WnA   = (float*)alloc((size_t)INF * HH * 4);
    float* WnB   = (float*)alloc((size_t)INF * HH * 4);
    float* WeC   = (float*)alloc((size_t)EDF * HH * 4);
    float* WeWo  = (float*)alloc((size_t)EDF * HH * DD * 4);
    float* WnWo  = (float*)alloc((size_t)INF * DD * 4);
    float* an    = (float*)alloc((size_t)N * HH * 4);
    float* bn    = (float*)alloc((size_t)N * HH * 4);
    float* wep   = (float*)alloc((size_t)E * HH * 4);
    float* EFp   = (float*)alloc((size_t)E * EDF * 4);
    float* Ghat  = (float*)alloc((size_t)N * 256 * 4);
    int* deg     = (int*)alloc((size_t)N * 4);
    int* offs    = (int*)alloc((size_t)N * 4);
    int2* nd     = (int2*)alloc((size_t)N * 8);
    int* rank    = (int*)alloc((size_t)E * 4);
    int* pos_of  = (int*)alloc((size_t)E * 4);
    int* partial = (int*)alloc((size_t)NB * 4);
    int* pscan   = (int*)alloc((size_t)NB * 4);

    int chunk = (N + NB - 1) / NB;

    hipLaunchKernelGGL(k_pre, dim3(25), dim3(512), 0, stream,
                       Wn, We, Wa, Wo, WnA, WnB, WeC, WeWo, WnWo);
    hipLaunchKernelGGL(k_nodes, dim3((N + 3) / 4), dim3(256), 0, stream,
                       node_feats, WnA, WnB, an, bn, N);
    hipLaunchKernelGGL(k_init, dim3((N + 255) / 256), dim3(256), 0, stream, deg, N);
    hipLaunchKernelGGL(k_hist, dim3((E + 255) / 256), dim3(256), 0, stream,
                       dst, deg, rank, E);
    hipLaunchKernelGGL(k_scan1, dim3(NB), dim3(256), 0, stream, deg, partial, N, chunk);
    hipLaunchKernelGGL(k_scan2, dim3(1), dim3(NB), 0, stream, partial, pscan);
    hipLaunchKernelGGL(k_scan3, dim3(NB), dim3(256), 0, stream, deg, pscan, offs, nd, N, chunk);
    hipLaunchKernelGGL(k_pos, dim3((E + 255) / 256), dim3(256), 0, stream,
                       dst, offs, rank, pos_of, E);
    hipLaunchKernelGGL(k_logit, dim3((E + 15) / 16), dim3(256), 0, stream,
                       edge_feats, an, bn, WeC, src, dst, pos_of, wep, EFp, E);
    hipLaunchKernelGGL(k_agg, dim3((N + 3) / 4), dim3(256), 0, stream,
                       EFp, wep, nd, Ghat, N);
    hipLaunchKernelGGL(k_out, dim3((N + ONODES - 1) / ONODES), dim3(256), 0, stream,
                       Ghat, WeWo, node_feats, WnWo, deg, out, N);
}

// Round 5
// 221.184 us; speedup vs baseline: 1.1838x; 1.1838x over previous
//
#include <hip/hip_runtime.h>
#include <hip/hip_fp16.h>
#include <math.h>

#define HH 4      // heads
#define DD 32     // out dim per head
#define HD 128    // H*D
#define INF 128   // node in_dim
#define EDF 64    // edge feat dim
#define NEG 0.01f
#define NB 256    // scan blocks
#define CHUNK 64  // edges per k_agg chunk

// ---- DPP butterfly add within rows of 16 lanes (VALU, no LDS) -----------
template <int CTRL>
__device__ __forceinline__ float dpp_add(float v) {
    int t = __builtin_amdgcn_update_dpp(0, __float_as_int(v), CTRL, 0xF, 0xF, true);
    return v + __int_as_float(t);
}
__device__ __forceinline__ float red16(float v) {
    v = dpp_add<0xB1>(v);    // quad_perm(1,0,3,2)
    v = dpp_add<0x4E>(v);    // quad_perm(2,3,0,1)
    v = dpp_add<0x141>(v);   // row_half_mirror
    v = dpp_add<0x140>(v);   // row_mirror
    return v;
}

// ---- precompute collapsed weight matrices -------------------------------
__global__ void k_pre(const float* __restrict__ Wn, const float* __restrict__ We,
                      const float* __restrict__ Wa, const float* __restrict__ Wo,
                      float* __restrict__ WnA, float* __restrict__ WnB,
                      float* __restrict__ WeC, float* __restrict__ WeWo,
                      float* __restrict__ WnWo) {
    int b = blockIdx.x, tid = threadIdx.x;   // 25 blocks x 512
    if (b < 16) {
        int t = b * 512 + tid;               // t = (h*64+k)*32 + o
        int j = t >> 5, o = t & 31;
        int h = j >> 6, k = j & 63;
        float a = 0.f;
        for (int d = 0; d < DD; ++d)
            a += We[k * HD + h * DD + d] * Wo[(h * DD + d) * DD + o];
        WeWo[t] = a;
    } else if (b < 24) {
        int u = (b - 16) * 512 + tid;        // u = k*32 + o
        int k = u >> 5, o = u & 31;
        float a = 0.f;
        for (int d = 0; d < HD; ++d)
            a += Wn[k * HD + d] * Wo[d * DD + o];
        WnWo[u] = a;
    } else {
        int k = tid >> 2, h = tid & 3;
        float a = 0.f, bb = 0.f;
        for (int d = 0; d < DD; ++d) {
            float w = Wn[k * HD + h * DD + d];
            a += w * Wa[d];
            bb += w * Wa[DD + d];
        }
        WnA[k * HH + h] = a;
        WnB[k * HH + h] = bb;
        if (k < EDF) {
            float c = 0.f;
            for (int d = 0; d < DD; ++d)
                c += We[k * HD + h * DD + d] * (Wa[d] + Wa[DD + d]);
            WeC[k * HH + h] = c;
        }
    }
}

// ---- per-node attention scalars an,bn (wave per node) -------------------
__global__ void k_nodes(const float* __restrict__ X, const float* __restrict__ WnA,
                        const float* __restrict__ WnB, float* __restrict__ an,
                        float* __restrict__ bn, int N) {
    int wave = threadIdx.x >> 6, lane = threadIdx.x & 63;
    int n = blockIdx.x * 4 + wave;
    if (n >= N) return;
    float x0 = X[(size_t)n * INF + lane];
    float x1 = X[(size_t)n * INF + 64 + lane];
    float pa[HH], pb[HH];
#pragma unroll
    for (int h = 0; h < HH; ++h) {
        pa[h] = x0 * WnA[lane * HH + h] + x1 * WnA[(lane + 64) * HH + h];
        pb[h] = x0 * WnB[lane * HH + h] + x1 * WnB[(lane + 64) * HH + h];
    }
#pragma unroll
    for (int off = 32; off; off >>= 1)
#pragma unroll
        for (int h = 0; h < HH; ++h) {
            pa[h] += __shfl_xor(pa[h], off);
            pb[h] += __shfl_xor(pb[h], off);
        }
    if (lane == 0)
#pragma unroll
        for (int h = 0; h < HH; ++h) {
            an[(size_t)n * HH + h] = pa[h];
            bn[(size_t)n * HH + h] = pb[h];
        }
}

// ---- CSR build ----------------------------------------------------------
__global__ void k_init(int* __restrict__ deg, int N) {
    int i = blockIdx.x * blockDim.x + threadIdx.x;
    if (i < N) deg[i] = 0;
}
__global__ void k_hist(const int* __restrict__ dst, int* __restrict__ deg,
                       int* __restrict__ rank, int E) {
    int e = blockIdx.x * blockDim.x + threadIdx.x;
    if (e < E) rank[e] = atomicAdd(&deg[dst[e]], 1);
}
__global__ void k_scan1(const int* __restrict__ deg, int* __restrict__ partial,
                        int N, int chunk) {
    __shared__ int s[256];
    int tid = threadIdx.x;
    int i = blockIdx.x * chunk + tid;
    int v = (tid < chunk && i < N) ? deg[i] : 0;
    s[tid] = v; __syncthreads();
    for (int off = 128; off; off >>= 1) {
        if (tid < off) s[tid] += s[tid + off];
        __syncthreads();
    }
    if (tid == 0) partial[blockIdx.x] = s[0];
}
__global__ void k_scan2(const int* __restrict__ partial, int* __restrict__ pscan) {
    __shared__ int s[NB];
    int tid = threadIdx.x;
    int v = partial[tid];
    s[tid] = v; __syncthreads();
    for (int off = 1; off < NB; off <<= 1) {
        int t = (tid >= off) ? s[tid - off] : 0;
        __syncthreads();
        s[tid] += t;
        __syncthreads();
    }
    pscan[tid] = s[tid] - v;   // exclusive
}
// packs nd[i] = {offs, deg} so k_agg loads node meta in ONE int2
__global__ void k_scan3(const int* __restrict__ deg, const int* __restrict__ pscan,
                        int* __restrict__ offs, int2* __restrict__ nd,
                        int N, int chunk) {
    __shared__ int s[256];
    int tid = threadIdx.x;
    int i = blockIdx.x * chunk + tid;
    int v = (tid < chunk && i < N) ? deg[i] : 0;
    s[tid] = v; __syncthreads();
    for (int off = 1; off < 256; off <<= 1) {
        int t = (tid >= off) ? s[tid - off] : 0;
        __syncthreads();
        s[tid] += t;
        __syncthreads();
    }
    if (tid < chunk && i < N) {
        int o = pscan[blockIdx.x] + s[tid] - v;   // exclusive
        offs[i] = o;
        nd[i] = make_int2(o, v);
    }
}
// forward AND inverse permutation in one pass
__global__ void k_perm(const int* __restrict__ dst, const int* __restrict__ offs,
                       const int* __restrict__ rank, int* __restrict__ eids,
                       int* __restrict__ pos_of, int E) {
    int e = blockIdx.x * blockDim.x + threadIdx.x;
    if (e < E) {
        int p = offs[dst[e]] + rank[e];
        pos_of[e] = p;
        eids[p] = e;
    }
}

// ---- edge-parallel logits + fp16 transcode + wep scatter ----------------
// wave handles 4 consecutive edges; 16 lanes per edge. Reads EF coalesced
// (storage order). Writes: EF16[e] fp16 row (coalesced, halves the bytes
// k_agg must gather) and wep[pos] (16B scatter, cheap). Logits in fp32.
__global__ void k_logit(const float* __restrict__ EF, const float* __restrict__ an,
                        const float* __restrict__ bn, const float* __restrict__ WeC,
                        const int* __restrict__ src, const int* __restrict__ dst,
                        const int* __restrict__ pos_of,
                        float* __restrict__ wep, __half* __restrict__ EF16, int E) {
    __shared__ float wec_s[EDF * HH];
    if (threadIdx.x < EDF * HH) wec_s[threadIdx.x] = WeC[threadIdx.x];
    __syncthreads();
    int wave = threadIdx.x >> 6, lane = threadIdx.x & 63;
    int g = lane >> 4, q = lane & 15;
    int e = (blockIdx.x * 4 + wave) * 4 + g;
    if (e >= E) return;
    float wc[4][4];
#pragma unroll
    for (int c = 0; c < 4; ++c)
#pragma unroll
        for (int h = 0; h < 4; ++h)
            wc[c][h] = wec_s[(q * 4 + c) * 4 + h];
    float4 x4 = *(const float4*)(EF + (size_t)e * EDF + q * 4);
    int s = src[e], d = dst[e], p = pos_of[e];
    float4 an4 = *(const float4*)(an + (size_t)s * HH);
    float4 bn4 = *(const float4*)(bn + (size_t)d * HH);
    float ae[4];
#pragma unroll
    for (int h = 0; h < 4; ++h) {
        float p0 = x4.x * wc[0][h] + x4.y * wc[1][h]
                 + x4.z * wc[2][h] + x4.w * wc[3][h];
        ae[h] = red16(p0);
    }
    // fp16 transcode, storage order (coalesced 128B per edge)
    __half2 h01 = __floats2half2_rn(x4.x, x4.y);
    __half2 h23 = __floats2half2_rn(x4.z, x4.w);
    __half2* hp = (__half2*)(EF16 + (size_t)e * EDF + q * 4);
    hp[0] = h01;
    hp[1] = h23;
    if (q == 0) {
        float l0 = an4.x + bn4.x + ae[0];
        float l1 = an4.y + bn4.y + ae[1];
        float l2 = an4.z + bn4.z + ae[2];
        float l3 = an4.w + bn4.w + ae[3];
        float4 w4;
        w4.x = __expf(l0 > 0.f ? l0 : NEG * l0);
        w4.y = __expf(l1 > 0.f ? l1 : NEG * l1);
        w4.z = __expf(l2 > 0.f ? l2 : NEG * l2);
        w4.w = __expf(l3 > 0.f ? l3 : NEG * l3);
        *(float4*)(wep + (size_t)p * 4) = w4;   // CSR-slot scatter (16B)
    }
}

// ---- aggregation + fused epilogue GEMM, v6 ------------------------------
// wave per node. wep contiguous per node; EF16 rows gathered (128B each,
// half the random bytes). After accumulation, normalized G (256 floats)
// is staged in LDS (reusing wbuf space) and multiplied by WeWo (32KB in
// LDS) to produce out[n][0..31] directly — Ghat round-trip eliminated.
__global__ void k_agg(const __half* __restrict__ EF16, const float* __restrict__ wep,
                      const int* __restrict__ eids, const int2* __restrict__ nd,
                      const float* __restrict__ WW, const float* __restrict__ X,
                      const float* __restrict__ WnWo, float* __restrict__ out, int N) {
    __shared__ float ww_s[256 * 32];         // WeWo, [j][o], 32KB
    __shared__ float smem[4][256];           // per-wave: wbuf (64xfloat4) then G
    __shared__ int   ebuf[4][CHUNK];
    for (int i = threadIdx.x; i < 256 * 32; i += 256)
        ww_s[i] = WW[i];
    __syncthreads();                         // only block-wide sync; before divergence

    int wave = threadIdx.x >> 6, lane = threadIdx.x & 63;
    int n = blockIdx.x * 4 + wave;
    if (n >= N) return;
    int2 sd = nd[n];
    int st = sd.x, dn = sd.y;

    if (dn == 0) {                           // rare: out = relu(X @ WnWo)
        if (lane < 32) {
            float a = 0.f;
            for (int k = 0; k < INF; ++k)
                a += X[(size_t)n * INF + k] * WnWo[k * DD + lane];
            out[(size_t)n * DD + lane] = fmaxf(a, 0.f);
        }
        return;
    }

    float4* wbuf = (float4*)smem[wave];
    const __half* base = EF16 + lane;
    float gacc[4] = {0.f, 0.f, 0.f, 0.f};
    float den[4]  = {0.f, 0.f, 0.f, 0.f};

    for (int r0 = 0; r0 < dn; r0 += CHUNK) {
        int cnt = dn - r0; if (cnt > CHUNK) cnt = CHUNK;
        // stage edge ids (coalesced) + weights (contiguous float4), pads w=0
        {
            int l2 = lane < cnt ? lane : cnt - 1;
            ebuf[wave][lane] = eids[st + r0 + l2];
            float4 w4 = *(const float4*)(wep + (size_t)(st + r0 + l2) * 4);
            if (lane >= cnt) w4 = make_float4(0.f, 0.f, 0.f, 0.f);
            wbuf[lane] = w4;
        }
        int nb4 = (cnt + 3) >> 2;
        // 2-deep prefetch of fp16 rows (128B per row per wave)
        __half x0[4], x1[4], x2[4];
        int ep[4];
#pragma unroll
        for (int j = 0; j < 4; ++j) ep[j] = ebuf[wave][j & 63];
#pragma unroll
        for (int j = 0; j < 4; ++j) x0[j] = base[(size_t)ep[j] * EDF];
#pragma unroll
        for (int j = 0; j < 4; ++j) ep[j] = ebuf[wave][(4 + j) & 63];
#pragma unroll
        for (int j = 0; j < 4; ++j) x1[j] = base[(size_t)ep[j] * EDF];
        for (int i = 0; i < nb4; ++i) {
#pragma unroll
            for (int j = 0; j < 4; ++j) ep[j] = ebuf[wave][((i + 2) * 4 + j) & 63];
#pragma unroll
            for (int j = 0; j < 4; ++j) x2[j] = base[(size_t)ep[j] * EDF];
            float f0 = __half2float(x0[0]), f1 = __half2float(x0[1]);
            float f2 = __half2float(x0[2]), f3 = __half2float(x0[3]);
            float4 wA = wbuf[i * 4 + 0];
            float4 wB = wbuf[i * 4 + 1];
            float4 wC = wbuf[i * 4 + 2];
            float4 wD = wbuf[i * 4 + 3];
            gacc[0] += wA.x * f0 + wB.x * f1 + wC.x * f2 + wD.x * f3;
            gacc[1] += wA.y * f0 + wB.y * f1 + wC.y * f2 + wD.y * f3;
            gacc[2] += wA.z * f0 + wB.z * f1 + wC.z * f2 + wD.z * f3;
            gacc[3] += wA.w * f0 + wB.w * f1 + wC.w * f2 + wD.w * f3;
            den[0] += wA.x + wB.x + wC.x + wD.x;
            den[1] += wA.y + wB.y + wC.y + wD.y;
            den[2] += wA.z + wB.z + wC.z + wD.z;
            den[3] += wA.w + wB.w + wC.w + wD.w;
#pragma unroll
            for (int j = 0; j < 4; ++j) { x0[j] = x1[j]; x1[j] = x2[j]; }
        }
    }
    // ---- fused epilogue: out[n][o] = relu( sum_j G[j]*WW[j][o] ) --------
    // stage normalized G in the (now free) wbuf space; intra-wave LDS
    // write->read (same pattern as wbuf staging above).
    float* G = smem[wave];
#pragma unroll
    for (int h = 0; h < 4; ++h)
        G[h * 64 + lane] = gacc[h] / den[h];
    int o = lane & 31, hi = lane >> 5;       // lane halves split the j-range
    float acc = 0.f;
    int j0 = hi * 128;
#pragma unroll 8
    for (int j = j0; j < j0 + 128; ++j)
        acc += G[j] * ww_s[j * 32 + o];
    acc += __shfl_xor(acc, 32);
    if (lane < 32)
        out[(size_t)n * DD + o] = fmaxf(acc, 0.f);
}

extern "C" void kernel_launch(void* const* d_in, const int* in_sizes, int n_in,
                              void* d_out, int out_size, void* d_ws, size_t ws_size,
                              hipStream_t stream) {
    const float* node_feats = (const float*)d_in[0];
    const float* edge_feats = (const float*)d_in[1];
    const int*   src        = (const int*)d_in[2];
    const int*   dst        = (const int*)d_in[3];
    const float* Wn         = (const float*)d_in[4];
    const float* We         = (const float*)d_in[5];
    const float* Wa         = (const float*)d_in[6];
    const float* Wo         = (const float*)d_in[7];
    float* out = (float*)d_out;
    int N = in_sizes[0] / INF;
    int E = in_sizes[2];

    char* p = (char*)d_ws;
    auto alloc = [&](size_t bytes) {
        char* r = p;
        p += (bytes + 255) & ~(size_t)255;
        return r;
    };
    float* WnA   = (float*)alloc((size_t)INF * HH * 4);
    float* WnB   = (float*)alloc((size_t)INF * HH * 4);
    float* WeC   = (float*)alloc((size_t)EDF * HH * 4);
    float* WeWo  = (float*)alloc((size_t)EDF * HH * DD * 4);
    float* WnWo  = (float*)alloc((size_t)INF * DD * 4);
    float* an    = (float*)alloc((size_t)N * HH * 4);
    float* bn    = (float*)alloc((size_t)N * HH * 4);
    float* wep   = (float*)alloc((size_t)E * HH * 4);
    __half* EF16 = (__half*)alloc((size_t)E * EDF * 2);
    int* deg     = (int*)alloc((size_t)N * 4);
    int* offs    = (int*)alloc((size_t)N * 4);
    int2* nd     = (int2*)alloc((size_t)N * 8);
    int* rank    = (int*)alloc((size_t)E * 4);
    int* eids    = (int*)alloc((size_t)E * 4);
    int* pos_of  = (int*)alloc((size_t)E * 4);
    int* partial = (int*)alloc((size_t)NB * 4);
    int* pscan   = (int*)alloc((size_t)NB * 4);

    int chunk = (N + NB - 1) / NB;

    hipLaunchKernelGGL(k_pre, dim3(25), dim3(512), 0, stream,
                       Wn, We, Wa, Wo, WnA, WnB, WeC, WeWo, WnWo);
    hipLaunchKernelGGL(k_nodes, dim3((N + 3) / 4), dim3(256), 0, stream,
                       node_feats, WnA, WnB, an, bn, N);
    hipLaunchKernelGGL(k_init, dim3((N + 255) / 256), dim3(256), 0, stream, deg, N);
    hipLaunchKernelGGL(k_hist, dim3((E + 255) / 256), dim3(256), 0, stream,
                       dst, deg, rank, E);
    hipLaunchKernelGGL(k_scan1, dim3(NB), dim3(256), 0, stream, deg, partial, N, chunk);
    hipLaunchKernelGGL(k_scan2, dim3(1), dim3(NB), 0, stream, partial, pscan);
    hipLaunchKernelGGL(k_scan3, dim3(NB), dim3(256), 0, stream, deg, pscan, offs, nd, N, chunk);
    hipLaunchKernelGGL(k_perm, dim3((E + 255) / 256), dim3(256), 0, stream,
                       dst, offs, rank, eids, pos_of, E);
    hipLaunchKernelGGL(k_logit, dim3((E + 15) / 16), dim3(256), 0, stream,
                       edge_feats, an, bn, WeC, src, dst, pos_of, wep, EF16, E);
    hipLaunchKernelGGL(k_agg, dim3((N + 3) / 4), dim3(256), 0, stream,
                       EF16, wep, eids, nd, WeWo, node_feats, WnWo, out, N);
}

// Round 6
// 202.219 us; speedup vs baseline: 1.2948x; 1.0938x over previous
//
#include <hip/hip_runtime.h>
#include <hip/hip_fp16.h>
#include <math.h>

#define HH 4      // heads
#define DD 32     // out dim per head
#define HD 128    // H*D
#define INF 128   // node in_dim
#define EDF 64    // edge feat dim
#define NEG 0.01f
#define NB 256    // scan blocks
#define CHUNK 64  // edges per k_agg chunk
#define GS_LOGIT 1024
#define GS_AGG   2048
#define GS_NODES 1024

// ---- DPP butterfly add within rows of 16 lanes (VALU, no LDS) -----------
template <int CTRL>
__device__ __forceinline__ float dpp_add(float v) {
    int t = __builtin_amdgcn_update_dpp(0, __float_as_int(v), CTRL, 0xF, 0xF, true);
    return v + __int_as_float(t);
}
__device__ __forceinline__ float red16(float v) {
    v = dpp_add<0xB1>(v);    // quad_perm(1,0,3,2)
    v = dpp_add<0x4E>(v);    // quad_perm(2,3,0,1)
    v = dpp_add<0x141>(v);   // row_half_mirror
    v = dpp_add<0x140>(v);   // row_mirror
    return v;
}

// ---- precompute collapsed weight matrices (+ zero deg, absorbing k_init) -
__global__ void k_pre(const float* __restrict__ Wn, const float* __restrict__ We,
                      const float* __restrict__ Wa, const float* __restrict__ Wo,
                      float* __restrict__ WnA, float* __restrict__ WnB,
                      float* __restrict__ WeC, float* __restrict__ WeWo,
                      float* __restrict__ WnWo, int* __restrict__ deg, int N) {
    int b = blockIdx.x, tid = threadIdx.x;   // (25 + ceil(N/512)) blocks x 512
    if (b >= 25) {
        int i = (b - 25) * 512 + tid;
        if (i < N) deg[i] = 0;
        return;
    }
    if (b < 16) {
        int t = b * 512 + tid;               // t = (h*64+k)*32 + o
        int j = t >> 5, o = t & 31;
        int h = j >> 6, k = j & 63;
        float a = 0.f;
        for (int d = 0; d < DD; ++d)
            a += We[k * HD + h * DD + d] * Wo[(h * DD + d) * DD + o];
        WeWo[t] = a;
    } else if (b < 24) {
        int u = (b - 16) * 512 + tid;        // u = k*32 + o
        int k = u >> 5, o = u & 31;
        float a = 0.f;
        for (int d = 0; d < HD; ++d)
            a += Wn[k * HD + d] * Wo[d * DD + o];
        WnWo[u] = a;
    } else {
        int k = tid >> 2, h = tid & 3;
        float a = 0.f, bb = 0.f;
        for (int d = 0; d < DD; ++d) {
            float w = Wn[k * HD + h * DD + d];
            a += w * Wa[d];
            bb += w * Wa[DD + d];
        }
        WnA[k * HH + h] = a;
        WnB[k * HH + h] = bb;
        if (k < EDF) {
            float c = 0.f;
            for (int d = 0; d < DD; ++d)
                c += We[k * HD + h * DD + d] * (Wa[d] + Wa[DD + d]);
            WeC[k * HH + h] = c;
        }
    }
}

// ---- per-node attention scalars an,bn (wave per node, grid-stride) ------
__global__ void k_nodes(const float* __restrict__ X, const float* __restrict__ WnA,
                        const float* __restrict__ WnB, float* __restrict__ an,
                        float* __restrict__ bn, int N) {
    int wave = threadIdx.x >> 6, lane = threadIdx.x & 63;
    int stride = gridDim.x * 4;
    for (int n = blockIdx.x * 4 + wave; n < N; n += stride) {
        float x0 = X[(size_t)n * INF + lane];
        float x1 = X[(size_t)n * INF + 64 + lane];
        float pa[HH], pb[HH];
#pragma unroll
        for (int h = 0; h < HH; ++h) {
            pa[h] = x0 * WnA[lane * HH + h] + x1 * WnA[(lane + 64) * HH + h];
            pb[h] = x0 * WnB[lane * HH + h] + x1 * WnB[(lane + 64) * HH + h];
        }
#pragma unroll
        for (int off = 32; off; off >>= 1)
#pragma unroll
            for (int h = 0; h < HH; ++h) {
                pa[h] += __shfl_xor(pa[h], off);
                pb[h] += __shfl_xor(pb[h], off);
            }
        if (lane == 0)
#pragma unroll
            for (int h = 0; h < HH; ++h) {
                an[(size_t)n * HH + h] = pa[h];
                bn[(size_t)n * HH + h] = pb[h];
            }
    }
}

// ---- CSR build ----------------------------------------------------------
__global__ void k_hist(const int* __restrict__ dst, int* __restrict__ deg,
                       int* __restrict__ rank, int E) {
    int e = blockIdx.x * blockDim.x + threadIdx.x;
    if (e < E) rank[e] = atomicAdd(&deg[dst[e]], 1);
}
__global__ void k_scan1(const int* __restrict__ deg, int* __restrict__ partial,
                        int N, int chunk) {
    __shared__ int s[256];
    int tid = threadIdx.x;
    int i = blockIdx.x * chunk + tid;
    int v = (tid < chunk && i < N) ? deg[i] : 0;
    s[tid] = v; __syncthreads();
    for (int off = 128; off; off >>= 1) {
        if (tid < off) s[tid] += s[tid + off];
        __syncthreads();
    }
    if (tid == 0) partial[blockIdx.x] = s[0];
}
__global__ void k_scan2(const int* __restrict__ partial, int* __restrict__ pscan) {
    __shared__ int s[NB];
    int tid = threadIdx.x;
    int v = partial[tid];
    s[tid] = v; __syncthreads();
    for (int off = 1; off < NB; off <<= 1) {
        int t = (tid >= off) ? s[tid - off] : 0;
        __syncthreads();
        s[tid] += t;
        __syncthreads();
    }
    pscan[tid] = s[tid] - v;   // exclusive
}
// packs nd[i] = {offs, deg}
__global__ void k_scan3(const int* __restrict__ deg, const int* __restrict__ pscan,
                        int* __restrict__ offs, int2* __restrict__ nd,
                        int N, int chunk) {
    __shared__ int s[256];
    int tid = threadIdx.x;
    int i = blockIdx.x * chunk + tid;
    int v = (tid < chunk && i < N) ? deg[i] : 0;
    s[tid] = v; __syncthreads();
    for (int off = 1; off < 256; off <<= 1) {
        int t = (tid >= off) ? s[tid - off] : 0;
        __syncthreads();
        s[tid] += t;
        __syncthreads();
    }
    if (tid < chunk && i < N) {
        int o = pscan[blockIdx.x] + s[tid] - v;   // exclusive
        offs[i] = o;
        nd[i] = make_int2(o, v);
    }
}
// forward AND inverse permutation in one pass
__global__ void k_perm(const int* __restrict__ dst, const int* __restrict__ offs,
                       const int* __restrict__ rank, int* __restrict__ eids,
                       int* __restrict__ pos_of, int E) {
    int e = blockIdx.x * blockDim.x + threadIdx.x;
    if (e < E) {
        int p = offs[dst[e]] + rank[e];
        pos_of[e] = p;
        eids[p] = e;
    }
}

// ---- edge-parallel logits + fp16 transcode, v3 --------------------------
// Persistent blocks, grid-stride over edge quads. 3-stage register
// pipeline: quad meta (EF row chunk, src, dst, pos) loaded 2 iters ahead,
// an/bn gathers issued 1 iter ahead -> every load has a full iteration
// (~hundreds of cycles) of latency cover. wc from global (1KB, L1
// broadcast) -> ZERO LDS, zero barriers, zero bank conflicts.
struct Quad { float4 x; int s, d, p, e; bool v; };

__device__ __forceinline__ Quad loadq(const float* __restrict__ EF,
                                      const int* __restrict__ src,
                                      const int* __restrict__ dst,
                                      const int* __restrict__ pos_of,
                                      int idx, int nq, int g, int q, int E) {
    Quad r;
    int qi = idx < nq ? idx : nq - 1;
    int e = qi * 4 + g;
    r.v = (idx < nq) && (e < E);
    if (e >= E) e = E - 1;
    r.e = e;
    r.x = *(const float4*)(EF + (size_t)e * EDF + q * 4);
    r.s = src[e];
    r.d = dst[e];
    r.p = pos_of[e];
    return r;
}

__global__ void k_logit(const float* __restrict__ EF, const float* __restrict__ an,
                        const float* __restrict__ bn, const float* __restrict__ WeC,
                        const int* __restrict__ src, const int* __restrict__ dst,
                        const int* __restrict__ pos_of,
                        float* __restrict__ wep, __half* __restrict__ EF16, int E) {
    int wave = threadIdx.x >> 6, lane = threadIdx.x & 63;
    int g = lane >> 4, q = lane & 15;
    // wc[c][h] = WeC[(q*4+c)*4+h]; 1KB table, L1-resident broadcast
    float4 c0 = *(const float4*)(WeC + (q * 4 + 0) * 4);
    float4 c1 = *(const float4*)(WeC + (q * 4 + 1) * 4);
    float4 c2 = *(const float4*)(WeC + (q * 4 + 2) * 4);
    float4 c3 = *(const float4*)(WeC + (q * 4 + 3) * 4);
    int nq = (E + 3) >> 2;
    int stride = gridDim.x * 4;
    int i0 = blockIdx.x * 4 + wave;
    if (i0 >= nq) return;
    Quad A = loadq(EF, src, dst, pos_of, i0, nq, g, q, E);
    Quad B = loadq(EF, src, dst, pos_of, i0 + stride, nq, g, q, E);
    float4 anA = *(const float4*)(an + (size_t)A.s * HH);
    float4 bnA = *(const float4*)(bn + (size_t)A.d * HH);
    for (int i = i0; i < nq; i += stride) {
        Quad C = loadq(EF, src, dst, pos_of, i + 2 * stride, nq, g, q, E);
        float4 anB = *(const float4*)(an + (size_t)B.s * HH);
        float4 bnB = *(const float4*)(bn + (size_t)B.d * HH);
        // 4 independent DPP-reduce chains (VALU pipe)
        float ae0 = red16(A.x.x * c0.x + A.x.y * c1.x + A.x.z * c2.x + A.x.w * c3.x);
        float ae1 = red16(A.x.x * c0.y + A.x.y * c1.y + A.x.z * c2.y + A.x.w * c3.y);
        float ae2 = red16(A.x.x * c0.z + A.x.y * c1.z + A.x.z * c2.z + A.x.w * c3.z);
        float ae3 = red16(A.x.x * c0.w + A.x.y * c1.w + A.x.z * c2.w + A.x.w * c3.w);
        if (A.v) {
            __half2 h01 = __floats2half2_rn(A.x.x, A.x.y);
            __half2 h23 = __floats2half2_rn(A.x.z, A.x.w);
            __half2* hp = (__half2*)(EF16 + (size_t)A.e * EDF + q * 4);
            hp[0] = h01;
            hp[1] = h23;
            if (q == 0) {
                float l0 = anA.x + bnA.x + ae0;
                float l1 = anA.y + bnA.y + ae1;
                float l2 = anA.z + bnA.z + ae2;
                float l3 = anA.w + bnA.w + ae3;
                float4 w4;
                w4.x = __expf(l0 > 0.f ? l0 : NEG * l0);
                w4.y = __expf(l1 > 0.f ? l1 : NEG * l1);
                w4.z = __expf(l2 > 0.f ? l2 : NEG * l2);
                w4.w = __expf(l3 > 0.f ? l3 : NEG * l3);
                *(float4*)(wep + (size_t)A.p * 4) = w4;   // 16B CSR-slot scatter
            }
        }
        A = B; anA = anB; bnA = bnB;
        B = C;
    }
}

// ---- aggregation + fused epilogue GEMM, v7 (grid-stride) ----------------
// WeWo staged ONCE per persistent block. Per node: contiguous wep read,
// fp16 EF row gathers (128B, 2-deep prefetch), lane=feature accumulate.
// Epilogue: G staged with stride-33 pad (conflict-free broadcast), WeWo
// read as float4 (64 LDS ops/node vs 256), 12-shuffle slice reduce,
// coalesced float4 out store.
__global__ void k_agg(const __half* __restrict__ EF16, const float* __restrict__ wep,
                      const int* __restrict__ eids, const int2* __restrict__ nd,
                      const float* __restrict__ WW, const float* __restrict__ X,
                      const float* __restrict__ WnWo, float* __restrict__ out, int N) {
    __shared__ float ww_s[256 * 32];         // [j][o] row-major, 32KB
    __shared__ float smem[4][264];           // per-wave: wbuf (1KB) / padded G
    __shared__ int   ebuf[4][CHUNK];
    for (int i = threadIdx.x; i < 256 * 32; i += 256)
        ww_s[i] = WW[i];
    __syncthreads();                         // once per block, before node loop

    int wave = threadIdx.x >> 6, lane = threadIdx.x & 63;
    int s8 = lane >> 3, o4 = lane & 7;       // epilogue: slice, out-quad
    int stride = gridDim.x * 4;
    for (int n = blockIdx.x * 4 + wave; n < N; n += stride) {
        int2 sd = nd[n];
        int st = sd.x, dn = sd.y;
        if (dn == 0) {                       // rare: out = relu(X @ WnWo)
            if (lane < 32) {
                float a = 0.f;
                for (int k = 0; k < INF; ++k)
                    a += X[(size_t)n * INF + k] * WnWo[k * DD + lane];
                out[(size_t)n * DD + lane] = fmaxf(a, 0.f);
            }
            continue;
        }
        float4* wbuf = (float4*)smem[wave];
        const __half* base = EF16 + lane;
        float gacc[4] = {0.f, 0.f, 0.f, 0.f};
        float den[4]  = {0.f, 0.f, 0.f, 0.f};
        for (int r0 = 0; r0 < dn; r0 += CHUNK) {
            int cnt = dn - r0; if (cnt > CHUNK) cnt = CHUNK;
            {
                int l2 = lane < cnt ? lane : cnt - 1;
                ebuf[wave][lane] = eids[st + r0 + l2];
                float4 w4 = *(const float4*)(wep + (size_t)(st + r0 + l2) * 4);
                if (lane >= cnt) w4 = make_float4(0.f, 0.f, 0.f, 0.f);
                wbuf[lane] = w4;
            }
            int nb4 = (cnt + 3) >> 2;
            __half x0[4], x1[4], x2[4];
            int ep[4];
#pragma unroll
            for (int j = 0; j < 4; ++j) ep[j] = ebuf[wave][j & 63];
#pragma unroll
            for (int j = 0; j < 4; ++j) x0[j] = base[(size_t)ep[j] * EDF];
#pragma unroll
            for (int j = 0; j < 4; ++j) ep[j] = ebuf[wave][(4 + j) & 63];
#pragma unroll
            for (int j = 0; j < 4; ++j) x1[j] = base[(size_t)ep[j] * EDF];
            for (int i = 0; i < nb4; ++i) {
#pragma unroll
                for (int j = 0; j < 4; ++j) ep[j] = ebuf[wave][((i + 2) * 4 + j) & 63];
#pragma unroll
                for (int j = 0; j < 4; ++j) x2[j] = base[(size_t)ep[j] * EDF];
                float f0 = __half2float(x0[0]), f1 = __half2float(x0[1]);
                float f2 = __half2float(x0[2]), f3 = __half2float(x0[3]);
                float4 wA = wbuf[i * 4 + 0];
                float4 wB = wbuf[i * 4 + 1];
                float4 wC = wbuf[i * 4 + 2];
                float4 wD = wbuf[i * 4 + 3];
                gacc[0] += wA.x * f0 + wB.x * f1 + wC.x * f2 + wD.x * f3;
                gacc[1] += wA.y * f0 + wB.y * f1 + wC.y * f2 + wD.y * f3;
                gacc[2] += wA.z * f0 + wB.z * f1 + wC.z * f2 + wD.z * f3;
                gacc[3] += wA.w * f0 + wB.w * f1 + wC.w * f2 + wD.w * f3;
                den[0] += wA.x + wB.x + wC.x + wD.x;
                den[1] += wA.y + wB.y + wC.y + wD.y;
                den[2] += wA.z + wB.z + wC.z + wD.z;
                den[3] += wA.w + wB.w + wC.w + wD.w;
#pragma unroll
                for (int j = 0; j < 4; ++j) { x0[j] = x1[j]; x1[j] = x2[j]; }
            }
        }
        // ---- fused epilogue ------------------------------------------
        float* G = smem[wave];               // reuse wbuf space, pad stride 33
#pragma unroll
        for (int h = 0; h < 4; ++h) {
            int idx = h * 64 + lane;
            G[idx + (idx >> 5)] = gacc[h] / den[h];
        }
        float4 acc = make_float4(0.f, 0.f, 0.f, 0.f);
        int jb = s8 * 32;
#pragma unroll 8
        for (int jj = 0; jj < 32; ++jj) {
            float gv = G[jb + jj + s8];      // conflict-free (stride-33)
            float4 w4 = *(const float4*)&ww_s[(jb + jj) * 32 + o4 * 4];
            acc.x += gv * w4.x;
            acc.y += gv * w4.y;
            acc.z += gv * w4.z;
            acc.w += gv * w4.w;
        }
#pragma unroll
        for (int off = 8; off < 64; off <<= 1) {
            acc.x += __shfl_xor(acc.x, off);
            acc.y += __shfl_xor(acc.y, off);
            acc.z += __shfl_xor(acc.z, off);
            acc.w += __shfl_xor(acc.w, off);
        }
        if (lane < 8) {                      // s8==0 holds full sums
            float4 o_;
            o_.x = fmaxf(acc.x, 0.f);
            o_.y = fmaxf(acc.y, 0.f);
            o_.z = fmaxf(acc.z, 0.f);
            o_.w = fmaxf(acc.w, 0.f);
            *(float4*)(out + (size_t)n * DD + o4 * 4) = o_;
        }
    }
}

extern "C" void kernel_launch(void* const* d_in, const int* in_sizes, int n_in,
                              void* d_out, int out_size, void* d_ws, size_t ws_size,
                              hipStream_t stream) {
    const float* node_feats = (const float*)d_in[0];
    const float* edge_feats = (const float*)d_in[1];
    const int*   src        = (const int*)d_in[2];
    const int*   dst        = (const int*)d_in[3];
    const float* Wn         = (const float*)d_in[4];
    const float* We         = (const float*)d_in[5];
    const float* Wa         = (const float*)d_in[6];
    const float* Wo         = (const float*)d_in[7];
    float* out = (float*)d_out;
    int N = in_sizes[0] / INF;
    int E = in_sizes[2];

    char* p = (char*)d_ws;
    auto alloc = [&](size_t bytes) {
        char* r = p;
        p += (bytes + 255) & ~(size_t)255;
        return r;
    };
    float* WnA   = (float*)alloc((size_t)INF * HH * 4);
    float* WnB   = (float*)alloc((size_t)INF * HH * 4);
    float* WeC   = (float*)alloc((size_t)EDF * HH * 4);
    float* WeWo  = (float*)alloc((size_t)EDF * HH * DD * 4);
    float* WnWo  = (float*)alloc((size_t)INF * DD * 4);
    float* an    = (float*)alloc((size_t)N * HH * 4);
    float* bn    = (float*)alloc((size_t)N * HH * 4);
    float* wep   = (float*)alloc((size_t)E * HH * 4);
    __half* EF16 = (__half*)alloc((size_t)E * EDF * 2);
    int* deg     = (int*)alloc((size_t)N * 4);
    int* offs    = (int*)alloc((size_t)N * 4);
    int2* nd     = (int2*)alloc((size_t)N * 8);
    int* rank    = (int*)alloc((size_t)E * 4);
    int* eids    = (int*)alloc((size_t)E * 4);
    int* pos_of  = (int*)alloc((size_t)E * 4);
    int* partial = (int*)alloc((size_t)NB * 4);
    int* pscan   = (int*)alloc((size_t)NB * 4);

    int chunk = (N + NB - 1) / NB;
    int preblk = 25 + (N + 511) / 512;

    hipLaunchKernelGGL(k_pre, dim3(preblk), dim3(512), 0, stream,
                       Wn, We, Wa, Wo, WnA, WnB, WeC, WeWo, WnWo, deg, N);
    hipLaunchKernelGGL(k_nodes, dim3(GS_NODES), dim3(256), 0, stream,
                       node_feats, WnA, WnB, an, bn, N);
    hipLaunchKernelGGL(k_hist, dim3((E + 255) / 256), dim3(256), 0, stream,
                       dst, deg, rank, E);
    hipLaunchKernelGGL(k_scan1, dim3(NB), dim3(256), 0, stream, deg, partial, N, chunk);
    hipLaunchKernelGGL(k_scan2, dim3(1), dim3(NB), 0, stream, partial, pscan);
    hipLaunchKernelGGL(k_scan3, dim3(NB), dim3(256), 0, stream, deg, pscan, offs, nd, N, chunk);
    hipLaunchKernelGGL(k_perm, dim3((E + 255) / 256), dim3(256), 0, stream,
                       dst, offs, rank, eids, pos_of, E);
    hipLaunchKernelGGL(k_logit, dim3(GS_LOGIT), dim3(256), 0, stream,
                       edge_feats, an, bn, WeC, src, dst, pos_of, wep, EF16, E);
    hipLaunchKernelGGL(k_agg, dim3(GS_AGG), dim3(256), 0, stream,
                       EF16, wep, eids, nd, WeWo, node_feats, WnWo, out, N);
}